// Round 3
// baseline (200.553 us; speedup 1.0000x reference)
//
#include <hip/hip_runtime.h>
#include <math.h>

// inputs/targets [32, 8, 256, 256] fp32; softmax over dim 1 (C=8).
constexpr int HW_ = 256 * 256;               // 65536
constexpr float FEPS = 1e-6f;
constexpr float NUM_COLS = 8.0f * 65536.0f;  // 524288

// Grid: 1024 blocks x 256 threads (target 6 blocks/CU = 24 waves/CU).
// Block covers 64 consecutive hw (lane = hw, scalar 4B loads, 256B/wave-instr
// coalesced). 4 batch-groups of 8 batches, one per wave.
__global__ __launch_bounds__(256, 6) void dice_main(const float* __restrict__ in,
                                                    const float* __restrict__ tg,
                                                    float* __restrict__ partial) {
    const int tid  = threadIdx.x;
    const int lane = tid & 63;
    const int bg   = tid >> 6;                  // 0..3
    const int hw0  = blockIdx.x * 64 + lane;

    float inter[8], den[8];
#pragma unroll
    for (int c = 0; c < 8; ++c) { inter[c] = 0.0f; den[c] = 0.0f; }

#pragma unroll
    for (int bi = 0; bi < 8; ++bi) {
        const int b    = bg * 8 + bi;
        const int base = b * 8 * HW_ + hw0;     // < 2^24, int math safe

        // Issue all 16 loads (8 in + 8 tg) before any compute.
        float xv[8], tv[8];
#pragma unroll
        for (int c = 0; c < 8; ++c) {
            xv[c] = in[base + c * HW_];
            tv[c] = tg[base + c * HW_];
        }

        float m = xv[0];
#pragma unroll
        for (int c = 1; c < 8; ++c) m = fmaxf(m, xv[c]);

        float e[8], s = 0.0f;
#pragma unroll
        for (int c = 0; c < 8; ++c) { e[c] = __expf(xv[c] - m); s += e[c]; }
        const float r = 1.0f / s;

#pragma unroll
        for (int c = 0; c < 8; ++c) {
            const float p = e[c] * r;
            inter[c] = fmaf(p, tv[c], inter[c]);
            den[c]  += p + tv[c];
        }
    }

    // Cross-wave (batch-group) reduction via LDS float atomics (ds_add_f32).
    // [64][17]: stride 17 (odd) -> lane*17 mod 32 is a permutation over 32
    // lanes, 2 lanes/bank = free (m136). Only 4.4 KB -> no LDS occupancy term.
    __shared__ float red[64][17];
    float* redf = &red[0][0];
    for (int i = tid; i < 64 * 17; i += 256) redf[i] = 0.0f;
    __syncthreads();
#pragma unroll
    for (int c = 0; c < 8; ++c) {
        atomicAdd(&red[lane][c],     inter[c]);
        atomicAdd(&red[lane][8 + c], den[c]);
    }
    __syncthreads();

    // 512 columns per block (64 hw x 8 c); 256 threads finish 2 each.
    float part = 0.0f;
#pragma unroll
    for (int k = 0; k < 2; ++k) {
        const int j   = tid + k * 256;
        const int hwi = j >> 3;
        const int c   = j & 7;
        part += (2.0f * red[hwi][c] + FEPS) / (red[hwi][8 + c] + FEPS);
    }

#pragma unroll
    for (int off = 32; off > 0; off >>= 1) part += __shfl_down(part, off, 64);

    __shared__ float wsum[4];
    if (lane == 0) wsum[bg] = part;
    __syncthreads();
    // Per-block partial (overwrites poisoned d_ws; no memset dispatch needed).
    if (tid == 0) partial[blockIdx.x] = wsum[0] + wsum[1] + wsum[2] + wsum[3];
}

__global__ __launch_bounds__(256) void dice_final(const float* __restrict__ partial,
                                                  float* __restrict__ out) {
    const int tid = threadIdx.x;  // 256 threads, 1024 partials
    float s = partial[tid] + partial[tid + 256] + partial[tid + 512] + partial[tid + 768];
#pragma unroll
    for (int off = 32; off > 0; off >>= 1) s += __shfl_down(s, off, 64);
    __shared__ float ws[4];
    if ((tid & 63) == 0) ws[tid >> 6] = s;
    __syncthreads();
    if (tid == 0) out[0] = 1.0f - (ws[0] + ws[1] + ws[2] + ws[3]) * (1.0f / NUM_COLS);
}

extern "C" void kernel_launch(void* const* d_in, const int* in_sizes, int n_in,
                              void* d_out, int out_size, void* d_ws, size_t ws_size,
                              hipStream_t stream) {
    const float* in = (const float*)d_in[0];
    const float* tg = (const float*)d_in[1];
    float* out = (float*)d_out;
    float* partial = (float*)d_ws;   // 1024 floats, fully overwritten each call

    dice_main<<<dim3(1024), dim3(256), 0, stream>>>(in, tg, partial);
    dice_final<<<dim3(1), dim3(256), 0, stream>>>(partial, out);
}

// Round 4
// 165.109 us; speedup vs baseline: 1.2147x; 1.2147x over previous
//
#include <hip/hip_runtime.h>
#include <math.h>

// inputs/targets [32, 8, 256, 256] fp32; softmax over dim 1 (C=8).
constexpr int HW_ = 256 * 256;               // 65536
constexpr float FEPS = 1e-6f;
constexpr float NUM_COLS = 8.0f * 65536.0f;  // 524288

// Grid: 512 blocks x 512 threads = 16 waves/CU (2 blocks/CU, LDS-gated).
// Block covers 128 consecutive hw (lane*2, float2). Wave w handles batches
// 4w..4w+3; cross-wave (batch) reduction via LDS tree, no atomic contention.
// Last block folds the final reduction (no separate finalize kernel).
__global__ __launch_bounds__(512, 4) void dice_main(const float* __restrict__ in,
                                                    const float* __restrict__ tg,
                                                    float* __restrict__ accum,
                                                    unsigned int* __restrict__ counter,
                                                    float* __restrict__ out) {
    const int tid  = threadIdx.x;
    const int lane = tid & 63;
    const int w    = tid >> 6;                 // wave id 0..7
    const int hw0  = blockIdx.x * 128 + lane * 2;

    float inter[2][8], den[2][8];
#pragma unroll
    for (int v = 0; v < 2; ++v)
#pragma unroll
        for (int c = 0; c < 8; ++c) { inter[v][c] = 0.0f; den[v][c] = 0.0f; }

#pragma unroll
    for (int bi = 0; bi < 4; ++bi) {
        const int b    = w * 4 + bi;
        const int base = b * 8 * HW_ + hw0;    // < 2^24, int math safe

        // All 16 loads (8 in + 8 tg) issued before any compute.
        float2 xv[8], tv[8];
#pragma unroll
        for (int c = 0; c < 8; ++c) {
            xv[c] = *reinterpret_cast<const float2*>(in + base + c * HW_);
            tv[c] = *reinterpret_cast<const float2*>(tg + base + c * HW_);
        }

        float m0 = xv[0].x, m1 = xv[0].y;
#pragma unroll
        for (int c = 1; c < 8; ++c) { m0 = fmaxf(m0, xv[c].x); m1 = fmaxf(m1, xv[c].y); }

        float e0[8], e1[8], s0 = 0.0f, s1 = 0.0f;
#pragma unroll
        for (int c = 0; c < 8; ++c) {
            e0[c] = __expf(xv[c].x - m0); s0 += e0[c];
            e1[c] = __expf(xv[c].y - m1); s1 += e1[c];
        }
        const float r0 = 1.0f / s0;
        const float r1 = 1.0f / s1;

#pragma unroll
        for (int c = 0; c < 8; ++c) {
            const float p0 = e0[c] * r0;
            const float p1 = e1[c] * r1;
            inter[0][c] = fmaf(p0, tv[c].x, inter[0][c]);
            inter[1][c] = fmaf(p1, tv[c].y, inter[1][c]);
            den[0][c] += p0 + tv[c].x;
            den[1][c] += p1 + tv[c].y;
        }
    }

    // Cross-wave (batch-group) reduction: 8 partial sets, LDS tree.
    // [8][64][33]: stride 33 (odd) -> lane*33 mod 32 = lane -> conflict-free.
    __shared__ float red[8][64][33];
#pragma unroll
    for (int v = 0; v < 2; ++v)
#pragma unroll
        for (int c = 0; c < 8; ++c) {
            red[w][lane][v * 8 + c]      = inter[v][c];
            red[w][lane][16 + v * 8 + c] = den[v][c];
        }
    __syncthreads();

    // 1024 columns per block (128 hw x 8 c); 512 threads finish 2 each.
    float part = 0.0f;
#pragma unroll
    for (int i = 0; i < 2; ++i) {
        const int j    = tid * 2 + i;      // 0..1023
        const int hw_l = j >> 3;           // 0..127
        const int c    = j & 7;
        const int ln   = hw_l >> 1;
        const int v    = hw_l & 1;
        float I = 0.0f, D = 0.0f;
#pragma unroll
        for (int ww = 0; ww < 8; ++ww) {
            I += red[ww][ln][v * 8 + c];
            D += red[ww][ln][16 + v * 8 + c];
        }
        part += (2.0f * I + FEPS) / (D + FEPS);
    }

#pragma unroll
    for (int off = 32; off > 0; off >>= 1) part += __shfl_down(part, off, 64);

    __shared__ float wsum[8];
    if (lane == 0) wsum[w] = part;
    __syncthreads();

    if (tid == 0) {
        float bs = 0.0f;
#pragma unroll
        for (int ww = 0; ww < 8; ++ww) bs += wsum[ww];
        atomicAdd(accum, bs);
        __threadfence();                              // device-scope publish
        const unsigned int done = atomicAdd(counter, 1u);
        if (done == gridDim.x - 1) {                  // last block finalizes
            const float tot = atomicAdd(accum, 0.0f); // atomic read-back (L2)
            out[0] = 1.0f - tot * (1.0f / NUM_COLS);
        }
    }
}

extern "C" void kernel_launch(void* const* d_in, const int* in_sizes, int n_in,
                              void* d_out, int out_size, void* d_ws, size_t ws_size,
                              hipStream_t stream) {
    const float* in = (const float*)d_in[0];
    const float* tg = (const float*)d_in[1];
    float* out = (float*)d_out;
    float* accum = (float*)d_ws;                       // ws[0]: float accum
    unsigned int* counter = (unsigned int*)d_ws + 1;   // ws[1]: block counter

    // d_ws is re-poisoned to 0xAA before every timed launch -> zero both words.
    hipMemsetAsync(d_ws, 0, 8, stream);
    dice_main<<<dim3(HW_ / 128), dim3(512), 0, stream>>>(in, tg, accum, counter, out);
}